// Round 1
// baseline (5143.077 us; speedup 1.0000x reference)
//
#include <hip/hip_runtime.h>
#include <math.h>

#define TT   1024   // B*S tokens
#define DM   768
#define NH   12
#define HD   64
#define FFD  2048
#define NE   8
#define SQ   512
#define NB   2
#define NL   4
#define NV   32000
#define REPS 1e-6f

// ---------------- embedding ----------------
__global__ __launch_bounds__(256) void k_embed(const int* __restrict__ ids,
    const float* __restrict__ tok, const float* __restrict__ pos, float* __restrict__ x) {
  int t = blockIdx.x; int s = t % SQ; int id = ids[t];
  for (int d = threadIdx.x; d < DM; d += 256)
    x[t * DM + d] = tok[(size_t)id * DM + d] + pos[s * DM + d];
}

// ---------------- rmsnorm ----------------
__global__ __launch_bounds__(256) void k_rmsnorm(const float* __restrict__ x,
    const float* __restrict__ w, float* __restrict__ y) {
  __shared__ float red[256];
  int t = blockIdx.x, tid = threadIdx.x;
  float ss = 0.f;
  for (int d = tid; d < DM; d += 256) { float v = x[t * DM + d]; ss += v * v; }
  red[tid] = ss; __syncthreads();
  for (int s = 128; s > 0; s >>= 1) { if (tid < s) red[tid] += red[tid + s]; __syncthreads(); }
  float inv = 1.0f / sqrtf(red[0] / (float)DM + REPS);
  for (int d = tid; d < DM; d += 256)
    y[t * DM + d] = w[d] * x[t * DM + d] * inv;
}

// ---------------- generic fp32 GEMM: C[M,N] = A[M,K] @ B[K,N] (+Cadd) ----------------
// M,N multiples of 64; K multiple of 16. grid (N/64, M/64), block 256.
__global__ __launch_bounds__(256) void k_gemm64(const float* __restrict__ A,
    const float* __restrict__ B, const float* __restrict__ Cadd, float* __restrict__ C,
    int M, int N, int K) {
  __shared__ float As[16][64];
  __shared__ float Bs[16][64];
  int tid = threadIdx.x;
  int m0 = blockIdx.y * 64, n0 = blockIdx.x * 64;
  int ty = tid >> 4, tx = tid & 15;
  int arow = tid >> 2, akf = (tid & 3) * 4;
  int bk = tid >> 4, bnf = (tid & 15) * 4;
  float acc[4][4] = {};
  for (int k0 = 0; k0 < K; k0 += 16) {
    float4 a = *(const float4*)&A[(size_t)(m0 + arow) * K + k0 + akf];
    As[akf + 0][arow] = a.x; As[akf + 1][arow] = a.y;
    As[akf + 2][arow] = a.z; As[akf + 3][arow] = a.w;
    *(float4*)&Bs[bk][bnf] = *(const float4*)&B[(size_t)(k0 + bk) * N + n0 + bnf];
    __syncthreads();
#pragma unroll
    for (int k = 0; k < 16; ++k) {
      float4 av = *(const float4*)&As[k][ty * 4];
      float4 bv = *(const float4*)&Bs[k][tx * 4];
      float avv[4] = {av.x, av.y, av.z, av.w};
      float bvv[4] = {bv.x, bv.y, bv.z, bv.w};
#pragma unroll
      for (int i = 0; i < 4; ++i)
#pragma unroll
        for (int j = 0; j < 4; ++j) acc[i][j] += avv[i] * bvv[j];
    }
    __syncthreads();
  }
#pragma unroll
  for (int i = 0; i < 4; ++i) {
    int r = m0 + ty * 4 + i;
    size_t base = (size_t)r * N + n0 + tx * 4;
    float4 o = make_float4(acc[i][0], acc[i][1], acc[i][2], acc[i][3]);
    if (Cadd) {
      float4 c = *(const float4*)&Cadd[base];
      o.x += c.x; o.y += c.y; o.z += c.z; o.w += c.w;
    }
    *(float4*)&C[base] = o;
  }
}

// ---------------- fused attention: one block per (b,h,q-row) ----------------
__global__ __launch_bounds__(256) void k_attn(const float* __restrict__ Q,
    const float* __restrict__ K, const float* __restrict__ V, float* __restrict__ O) {
  __shared__ float qrow[HD];
  __shared__ float sc[SQ];
  __shared__ float red[256];
  __shared__ float pv[4][HD];
  int idx = blockIdx.x;
  int s = idx % SQ; int h = (idx / SQ) % NH; int b = idx / (SQ * NH);
  int tid = threadIdx.x;
  size_t qbase = ((size_t)(b * SQ + s)) * DM + h * HD;
  if (tid < HD) qrow[tid] = Q[qbase + tid];
  __syncthreads();
  // scores (each thread: 2 keys)
  for (int kk = tid; kk < SQ; kk += 256) {
    const float4* kp = (const float4*)&K[((size_t)(b * SQ + kk)) * DM + h * HD];
    float dot = 0.f;
#pragma unroll
    for (int i = 0; i < HD / 4; ++i) {
      float4 kv = kp[i];
      dot += kv.x * qrow[4 * i] + kv.y * qrow[4 * i + 1]
           + kv.z * qrow[4 * i + 2] + kv.w * qrow[4 * i + 3];
    }
    sc[kk] = dot * 0.125f;
  }
  __syncthreads();
  // softmax (max)
  float m = fmaxf(sc[tid], sc[tid + 256]);
  red[tid] = m; __syncthreads();
  for (int r = 128; r > 0; r >>= 1) { if (tid < r) red[tid] = fmaxf(red[tid], red[tid + r]); __syncthreads(); }
  m = red[0]; __syncthreads();
  float e0 = expf(sc[tid] - m), e1 = expf(sc[tid + 256] - m);
  sc[tid] = e0; sc[tid + 256] = e1;
  red[tid] = e0 + e1; __syncthreads();
  for (int r = 128; r > 0; r >>= 1) { if (tid < r) red[tid] += red[tid + r]; __syncthreads(); }
  float inv = 1.0f / red[0];
  __syncthreads();
  // PV: 4 k-groups x 64 dims
  int g = tid >> 6, d = tid & 63;
  float accv = 0.f;
  for (int kk = g; kk < SQ; kk += 4)
    accv += sc[kk] * V[((size_t)(b * SQ + kk)) * DM + h * HD + d];
  pv[g][d] = accv; __syncthreads();
  if (g == 0)
    O[qbase + d] = (pv[0][d] + pv[1][d] + pv[2][d] + pv[3][d]) * inv;
}

// ---------------- MoE router: one wave per token ----------------
__global__ __launch_bounds__(64) void k_router(const float* __restrict__ xn,
    const float* __restrict__ rw, int* __restrict__ topi, float* __restrict__ topw,
    int* __restrict__ posb, int* __restrict__ slot, int* __restrict__ counts) {
  int t = blockIdx.x, l = threadIdx.x;
  float acc[NE] = {};
  for (int d = l; d < DM; d += 64) {
    float xv = xn[t * DM + d];
    const float* r = &rw[d * NE];
#pragma unroll
    for (int e = 0; e < NE; ++e) acc[e] += xv * r[e];
  }
#pragma unroll
  for (int off = 32; off > 0; off >>= 1)
#pragma unroll
    for (int e = 0; e < NE; ++e) acc[e] += __shfl_down(acc[e], off, 64);
  if (l == 0) {
    float mx = acc[0];
#pragma unroll
    for (int e = 1; e < NE; ++e) mx = fmaxf(mx, acc[e]);
    float p[NE], sum = 0.f;
#pragma unroll
    for (int e = 0; e < NE; ++e) { p[e] = expf(acc[e] - mx); sum += p[e]; }
#pragma unroll
    for (int e = 0; e < NE; ++e) p[e] /= sum;
    int i0 = 0;
    for (int e = 1; e < NE; ++e) if (p[e] > p[i0]) i0 = e;
    int i1 = (i0 == 0) ? 1 : 0;
    for (int e = 0; e < NE; ++e) if (e != i0 && p[e] > p[i1]) i1 = e;
    float w0 = p[i0], w1 = p[i1], inv = 1.f / (w0 + w1);
    w0 *= inv; w1 *= inv;
    int p0 = atomicAdd(&counts[i0], 1);
    int p1 = atomicAdd(&counts[i1], 1);
    topi[2 * t] = i0; topi[2 * t + 1] = i1;
    topw[2 * t] = w0; topw[2 * t + 1] = w1;
    posb[2 * t] = p0; posb[2 * t + 1] = p1;
    slot[i0 * TT + p0] = t; slot[i1 * TT + p1] = t;
  }
}

__global__ void k_zero8(int* c) { if (threadIdx.x < NE) c[threadIdx.x] = 0; }

__global__ void k_offsets(const int* __restrict__ counts, int* __restrict__ off) {
  int a = 0;
  for (int e = 0; e < NE; ++e) { off[e] = a; a += counts[e]; }
  off[NE] = a;
}

// ---------------- MoE gate+up (gathered rows) -> H = silu(G)*U ----------------
__global__ __launch_bounds__(256) void k_moe_gu(const float* __restrict__ xn,
    const float* __restrict__ gw, const float* __restrict__ uw,
    const int* __restrict__ slot, const int* __restrict__ counts,
    const int* __restrict__ offs, float* __restrict__ H) {
  int e = blockIdx.z;
  int cnt = counts[e];
  int m0 = blockIdx.y * 64;
  if (m0 >= cnt) return;
  int n0 = blockIdx.x * 64;
  __shared__ float As[16][64], Bg[16][64], Bu[16][64];
  int tid = threadIdx.x;
  int ty = tid >> 4, tx = tid & 15;
  int arow = tid >> 2, akf = (tid & 3) * 4;
  int bk = tid >> 4, bnf = (tid & 15) * 4;
  float aG[4][4] = {}, aU[4][4] = {};
  int grow = m0 + arow;
  const float* arp = nullptr;
  if (grow < cnt) arp = &xn[(size_t)slot[e * TT + grow] * DM];
  const float* gwe = gw + (size_t)e * DM * FFD;
  const float* uwe = uw + (size_t)e * DM * FFD;
  for (int k0 = 0; k0 < DM; k0 += 16) {
    float4 a = make_float4(0.f, 0.f, 0.f, 0.f);
    if (arp) a = *(const float4*)&arp[k0 + akf];
    As[akf + 0][arow] = a.x; As[akf + 1][arow] = a.y;
    As[akf + 2][arow] = a.z; As[akf + 3][arow] = a.w;
    *(float4*)&Bg[bk][bnf] = *(const float4*)&gwe[(size_t)(k0 + bk) * FFD + n0 + bnf];
    *(float4*)&Bu[bk][bnf] = *(const float4*)&uwe[(size_t)(k0 + bk) * FFD + n0 + bnf];
    __syncthreads();
#pragma unroll
    for (int k = 0; k < 16; ++k) {
      float4 av = *(const float4*)&As[k][ty * 4];
      float4 bg = *(const float4*)&Bg[k][tx * 4];
      float4 bu = *(const float4*)&Bu[k][tx * 4];
      float avv[4] = {av.x, av.y, av.z, av.w};
      float bgv[4] = {bg.x, bg.y, bg.z, bg.w};
      float buv[4] = {bu.x, bu.y, bu.z, bu.w};
#pragma unroll
      for (int i = 0; i < 4; ++i)
#pragma unroll
        for (int j = 0; j < 4; ++j) {
          aG[i][j] += avv[i] * bgv[j];
          aU[i][j] += avv[i] * buv[j];
        }
    }
    __syncthreads();
  }
  int off = offs[e];
#pragma unroll
  for (int i = 0; i < 4; ++i) {
    int r = m0 + ty * 4 + i;
    if (r < cnt) {
      float o[4];
#pragma unroll
      for (int j = 0; j < 4; ++j) {
        float g = aG[i][j];
        o[j] = (g / (1.f + expf(-g))) * aU[i][j];
      }
      *(float4*)&H[(size_t)(off + r) * FFD + n0 + tx * 4] = make_float4(o[0], o[1], o[2], o[3]);
    }
  }
}

// ---------------- MoE down: eo = H @ dw[e] ----------------
__global__ __launch_bounds__(256) void k_moe_down(const float* __restrict__ H,
    const float* __restrict__ dw, const int* __restrict__ counts,
    const int* __restrict__ offs, float* __restrict__ eo) {
  int e = blockIdx.z;
  int cnt = counts[e];
  int m0 = blockIdx.y * 64;
  if (m0 >= cnt) return;
  int n0 = blockIdx.x * 64;
  __shared__ float As[16][64], Bs[16][64];
  int tid = threadIdx.x;
  int ty = tid >> 4, tx = tid & 15;
  int arow = tid >> 2, akf = (tid & 3) * 4;
  int bk = tid >> 4, bnf = (tid & 15) * 4;
  float acc[4][4] = {};
  int off = offs[e];
  int grow = m0 + arow;
  const float* arp = (grow < cnt) ? &H[(size_t)(off + grow) * FFD] : nullptr;
  const float* dwe = dw + (size_t)e * FFD * DM;
  for (int k0 = 0; k0 < FFD; k0 += 16) {
    float4 a = make_float4(0.f, 0.f, 0.f, 0.f);
    if (arp) a = *(const float4*)&arp[k0 + akf];
    As[akf + 0][arow] = a.x; As[akf + 1][arow] = a.y;
    As[akf + 2][arow] = a.z; As[akf + 3][arow] = a.w;
    *(float4*)&Bs[bk][bnf] = *(const float4*)&dwe[(size_t)(k0 + bk) * DM + n0 + bnf];
    __syncthreads();
#pragma unroll
    for (int k = 0; k < 16; ++k) {
      float4 av = *(const float4*)&As[k][ty * 4];
      float4 bv = *(const float4*)&Bs[k][tx * 4];
      float avv[4] = {av.x, av.y, av.z, av.w};
      float bvv[4] = {bv.x, bv.y, bv.z, bv.w};
#pragma unroll
      for (int i = 0; i < 4; ++i)
#pragma unroll
        for (int j = 0; j < 4; ++j) acc[i][j] += avv[i] * bvv[j];
    }
    __syncthreads();
  }
#pragma unroll
  for (int i = 0; i < 4; ++i) {
    int r = m0 + ty * 4 + i;
    if (r < cnt)
      *(float4*)&eo[(size_t)(off + r) * DM + n0 + tx * 4] =
          make_float4(acc[i][0], acc[i][1], acc[i][2], acc[i][3]);
  }
}

// ---------------- combine: x[t] += w0*eo[r0] + w1*eo[r1] (deterministic) ----------------
__global__ __launch_bounds__(256) void k_combine(const float* __restrict__ eo,
    const int* __restrict__ topi, const float* __restrict__ topw,
    const int* __restrict__ posb, const int* __restrict__ offs, float* __restrict__ x) {
  int t = blockIdx.x;
  int r0 = offs[topi[2 * t]] + posb[2 * t];
  int r1 = offs[topi[2 * t + 1]] + posb[2 * t + 1];
  float w0 = topw[2 * t], w1 = topw[2 * t + 1];
  for (int d = threadIdx.x; d < DM; d += 256)
    x[t * DM + d] += w0 * eo[(size_t)r0 * DM + d] + w1 * eo[(size_t)r1 * DM + d];
}

extern "C" void kernel_launch(void* const* d_in, const int* in_sizes, int n_in,
                              void* d_out, int out_size, void* d_ws, size_t ws_size,
                              hipStream_t stream) {
  (void)in_sizes; (void)n_in; (void)out_size; (void)ws_size;
  const int*   ids = (const int*)d_in[0];
  const float* tok = (const float*)d_in[1];
  const float* pos = (const float*)d_in[2];
  const float* wq  = (const float*)d_in[3];
  const float* wk  = (const float*)d_in[4];
  const float* wv  = (const float*)d_in[5];
  const float* wo  = (const float*)d_in[6];
  const float* n1w = (const float*)d_in[7];
  const float* n2w = (const float*)d_in[8];
  const float* rw  = (const float*)d_in[9];
  const float* gw  = (const float*)d_in[10];
  const float* uw  = (const float*)d_in[11];
  const float* dw  = (const float*)d_in[12];
  const float* fnw = (const float*)d_in[13];
  const float* lmw = (const float*)d_in[14];
  float* out = (float*)d_out;

  char* p = (char*)d_ws;
  auto alloc = [&](size_t bytes) { char* r = p; p += (bytes + 255) & ~(size_t)255; return r; };
  float* x    = (float*)alloc((size_t)TT * DM * 4);
  float* xn   = (float*)alloc((size_t)TT * DM * 4);
  float* q    = (float*)alloc((size_t)TT * DM * 4);
  float* kx   = (float*)alloc((size_t)TT * DM * 4);
  float* vx   = (float*)alloc((size_t)TT * DM * 4);
  float* ao   = (float*)alloc((size_t)TT * DM * 4);
  float* Hbuf = (float*)alloc((size_t)2 * TT * FFD * 4);
  float* eo   = (float*)alloc((size_t)2 * TT * DM * 4);
  float* topw = (float*)alloc((size_t)2 * TT * 4);
  int* topi   = (int*)alloc((size_t)2 * TT * 4);
  int* posb   = (int*)alloc((size_t)2 * TT * 4);
  int* slot   = (int*)alloc((size_t)NE * TT * 4);
  int* counts = (int*)alloc(256);
  int* offs   = (int*)alloc(256);

  k_embed<<<TT, 256, 0, stream>>>(ids, tok, pos, x);
  dim3 g12(DM / 64, TT / 64);
  for (int l = 0; l < NL; ++l) {
    k_rmsnorm<<<TT, 256, 0, stream>>>(x, n1w + l * DM, xn);
    k_gemm64<<<g12, 256, 0, stream>>>(xn, wq + (size_t)l * DM * DM, nullptr, q,  TT, DM, DM);
    k_gemm64<<<g12, 256, 0, stream>>>(xn, wk + (size_t)l * DM * DM, nullptr, kx, TT, DM, DM);
    k_gemm64<<<g12, 256, 0, stream>>>(xn, wv + (size_t)l * DM * DM, nullptr, vx, TT, DM, DM);
    k_attn<<<NB * NH * SQ, 256, 0, stream>>>(q, kx, vx, ao);
    k_gemm64<<<g12, 256, 0, stream>>>(ao, wo + (size_t)l * DM * DM, x, x, TT, DM, DM);
    k_rmsnorm<<<TT, 256, 0, stream>>>(x, n2w + l * DM, xn);
    k_zero8<<<1, 64, 0, stream>>>(counts);
    k_router<<<TT, 64, 0, stream>>>(xn, rw + (size_t)l * DM * NE, topi, topw, posb, slot, counts);
    k_offsets<<<1, 1, 0, stream>>>(counts, offs);
    k_moe_gu<<<dim3(FFD / 64, TT / 64, NE), 256, 0, stream>>>(
        xn, gw + (size_t)l * NE * DM * FFD, uw + (size_t)l * NE * DM * FFD,
        slot, counts, offs, Hbuf);
    k_moe_down<<<dim3(DM / 64, TT / 64, NE), 256, 0, stream>>>(
        Hbuf, dw + (size_t)l * NE * FFD * DM, counts, offs, eo);
    k_combine<<<TT, 256, 0, stream>>>(eo, topi, topw, posb, offs, x);
  }
  k_rmsnorm<<<TT, 256, 0, stream>>>(x, fnw, xn);
  k_gemm64<<<dim3(NV / 64, TT / 64), 256, 0, stream>>>(xn, lmw, nullptr, out, TT, NV, DM);
}

// Round 5
// 4762.183 us; speedup vs baseline: 1.0800x; 1.0800x over previous
//
#include <hip/hip_runtime.h>
#include <math.h>

#define TT   1024   // B*S tokens
#define DM   768
#define NH   12
#define HD   64
#define FFD  2048
#define NE   8
#define SQ   512
#define NB   2
#define NL   4
#define NV   32000
#define REPS 1e-6f
#define LMC  3200

typedef int   int4v __attribute__((ext_vector_type(4)));
typedef float f32x4 __attribute__((ext_vector_type(4)));
typedef short s16x8 __attribute__((ext_vector_type(8)));

__device__ __forceinline__ ushort f2b(float f) {
  unsigned i = __float_as_uint(f);
  return (ushort)((i + 0x7FFFu + ((i >> 16) & 1u)) >> 16);
}

// ================= r1 fp32 pipeline (verbatim, known-good) =================
__global__ __launch_bounds__(256) void k_embed(const int* __restrict__ ids,
    const float* __restrict__ tok, const float* __restrict__ pos, float* __restrict__ x) {
  int t = blockIdx.x; int s = t % SQ; int id = ids[t];
  for (int d = threadIdx.x; d < DM; d += 256)
    x[t * DM + d] = tok[(size_t)id * DM + d] + pos[s * DM + d];
}

__global__ __launch_bounds__(256) void k_rmsnorm(const float* __restrict__ x,
    const float* __restrict__ w, float* __restrict__ y) {
  __shared__ float red[256];
  int t = blockIdx.x, tid = threadIdx.x;
  float ss = 0.f;
  for (int d = tid; d < DM; d += 256) { float v = x[t * DM + d]; ss += v * v; }
  red[tid] = ss; __syncthreads();
  for (int s = 128; s > 0; s >>= 1) { if (tid < s) red[tid] += red[tid + s]; __syncthreads(); }
  float inv = 1.0f / sqrtf(red[0] / (float)DM + REPS);
  for (int d = tid; d < DM; d += 256)
    y[t * DM + d] = w[d] * x[t * DM + d] * inv;
}

__global__ __launch_bounds__(256) void k_gemm64(const float* __restrict__ A,
    const float* __restrict__ B, const float* __restrict__ Cadd, float* __restrict__ C,
    int M, int N, int K) {
  __shared__ float As[16][64];
  __shared__ float Bs[16][64];
  int tid = threadIdx.x;
  int m0 = blockIdx.y * 64, n0 = blockIdx.x * 64;
  int ty = tid >> 4, tx = tid & 15;
  int arow = tid >> 2, akf = (tid & 3) * 4;
  int bk = tid >> 4, bnf = (tid & 15) * 4;
  float acc[4][4] = {};
  for (int k0 = 0; k0 < K; k0 += 16) {
    float4 a = *(const float4*)&A[(size_t)(m0 + arow) * K + k0 + akf];
    As[akf + 0][arow] = a.x; As[akf + 1][arow] = a.y;
    As[akf + 2][arow] = a.z; As[akf + 3][arow] = a.w;
    *(float4*)&Bs[bk][bnf] = *(const float4*)&B[(size_t)(k0 + bk) * N + n0 + bnf];
    __syncthreads();
#pragma unroll
    for (int k = 0; k < 16; ++k) {
      float4 av = *(const float4*)&As[k][ty * 4];
      float4 bv = *(const float4*)&Bs[k][tx * 4];
      float avv[4] = {av.x, av.y, av.z, av.w};
      float bvv[4] = {bv.x, bv.y, bv.z, bv.w};
#pragma unroll
      for (int i = 0; i < 4; ++i)
#pragma unroll
        for (int j = 0; j < 4; ++j) acc[i][j] += avv[i] * bvv[j];
    }
    __syncthreads();
  }
#pragma unroll
  for (int i = 0; i < 4; ++i) {
    int r = m0 + ty * 4 + i;
    size_t base = (size_t)r * N + n0 + tx * 4;
    float4 o = make_float4(acc[i][0], acc[i][1], acc[i][2], acc[i][3]);
    if (Cadd) {
      float4 c = *(const float4*)&Cadd[base];
      o.x += c.x; o.y += c.y; o.z += c.z; o.w += c.w;
    }
    *(float4*)&C[base] = o;
  }
}

__global__ __launch_bounds__(256) void k_attn(const float* __restrict__ Q,
    const float* __restrict__ K, const float* __restrict__ V, float* __restrict__ O) {
  __shared__ float qrow[HD];
  __shared__ float sc[SQ];
  __shared__ float red[256];
  __shared__ float pv[4][HD];
  int idx = blockIdx.x;
  int s = idx % SQ; int h = (idx / SQ) % NH; int b = idx / (SQ * NH);
  int tid = threadIdx.x;
  size_t qbase = ((size_t)(b * SQ + s)) * DM + h * HD;
  if (tid < HD) qrow[tid] = Q[qbase + tid];
  __syncthreads();
  for (int kk = tid; kk < SQ; kk += 256) {
    const float4* kp = (const float4*)&K[((size_t)(b * SQ + kk)) * DM + h * HD];
    float dot = 0.f;
#pragma unroll
    for (int i = 0; i < HD / 4; ++i) {
      float4 kv = kp[i];
      dot += kv.x * qrow[4 * i] + kv.y * qrow[4 * i + 1]
           + kv.z * qrow[4 * i + 2] + kv.w * qrow[4 * i + 3];
    }
    sc[kk] = dot * 0.125f;
  }
  __syncthreads();
  float m = fmaxf(sc[tid], sc[tid + 256]);
  red[tid] = m; __syncthreads();
  for (int r = 128; r > 0; r >>= 1) { if (tid < r) red[tid] = fmaxf(red[tid], red[tid + r]); __syncthreads(); }
  m = red[0]; __syncthreads();
  float e0 = expf(sc[tid] - m), e1 = expf(sc[tid + 256] - m);
  sc[tid] = e0; sc[tid + 256] = e1;
  red[tid] = e0 + e1; __syncthreads();
  for (int r = 128; r > 0; r >>= 1) { if (tid < r) red[tid] += red[tid + r]; __syncthreads(); }
  float inv = 1.0f / red[0];
  __syncthreads();
  int g = tid >> 6, d = tid & 63;
  float accv = 0.f;
  for (int kk = g; kk < SQ; kk += 4)
    accv += sc[kk] * V[((size_t)(b * SQ + kk)) * DM + h * HD + d];
  pv[g][d] = accv; __syncthreads();
  if (g == 0)
    O[qbase + d] = (pv[0][d] + pv[1][d] + pv[2][d] + pv[3][d]) * inv;
}

__global__ __launch_bounds__(64) void k_router(const float* __restrict__ xn,
    const float* __restrict__ rw, int* __restrict__ topi, float* __restrict__ topw,
    int* __restrict__ posb, int* __restrict__ slot, int* __restrict__ counts) {
  int t = blockIdx.x, l = threadIdx.x;
  float acc[NE] = {};
  for (int d = l; d < DM; d += 64) {
    float xv = xn[t * DM + d];
    const float* r = &rw[d * NE];
#pragma unroll
    for (int e = 0; e < NE; ++e) acc[e] += xv * r[e];
  }
#pragma unroll
  for (int off = 32; off > 0; off >>= 1)
#pragma unroll
    for (int e = 0; e < NE; ++e) acc[e] += __shfl_down(acc[e], off, 64);
  if (l == 0) {
    float mx = acc[0];
#pragma unroll
    for (int e = 1; e < NE; ++e) mx = fmaxf(mx, acc[e]);
    float p[NE], sum = 0.f;
#pragma unroll
    for (int e = 0; e < NE; ++e) { p[e] = expf(acc[e] - mx); sum += p[e]; }
#pragma unroll
    for (int e = 0; e < NE; ++e) p[e] /= sum;
    int i0 = 0;
    for (int e = 1; e < NE; ++e) if (p[e] > p[i0]) i0 = e;
    int i1 = (i0 == 0) ? 1 : 0;
    for (int e = 0; e < NE; ++e) if (e != i0 && p[e] > p[i1]) i1 = e;
    float w0 = p[i0], w1 = p[i1], inv = 1.f / (w0 + w1);
    w0 *= inv; w1 *= inv;
    int p0 = atomicAdd(&counts[i0], 1);
    int p1 = atomicAdd(&counts[i1], 1);
    topi[2 * t] = i0; topi[2 * t + 1] = i1;
    topw[2 * t] = w0; topw[2 * t + 1] = w1;
    posb[2 * t] = p0; posb[2 * t + 1] = p1;
    slot[i0 * TT + p0] = t; slot[i1 * TT + p1] = t;
  }
}

__global__ void k_zero8(int* c) { if (threadIdx.x < NE) c[threadIdx.x] = 0; }

__global__ void k_offsets(const int* __restrict__ counts, int* __restrict__ off) {
  int a = 0;
  for (int e = 0; e < NE; ++e) { off[e] = a; a += counts[e]; }
  off[NE] = a;
}

__global__ __launch_bounds__(256) void k_moe_gu(const float* __restrict__ xn,
    const float* __restrict__ gw, const float* __restrict__ uw,
    const int* __restrict__ slot, const int* __restrict__ counts,
    const int* __restrict__ offs, float* __restrict__ H) {
  int e = blockIdx.z;
  int cnt = counts[e];
  int m0 = blockIdx.y * 64;
  if (m0 >= cnt) return;
  int n0 = blockIdx.x * 64;
  __shared__ float As[16][64], Bg[16][64], Bu[16][64];
  int tid = threadIdx.x;
  int ty = tid >> 4, tx = tid & 15;
  int arow = tid >> 2, akf = (tid & 3) * 4;
  int bk = tid >> 4, bnf = (tid & 15) * 4;
  float aG[4][4] = {}, aU[4][4] = {};
  int grow = m0 + arow;
  const float* arp = nullptr;
  if (grow < cnt) arp = &xn[(size_t)slot[e * TT + grow] * DM];
  const float* gwe = gw + (size_t)e * DM * FFD;
  const float* uwe = uw + (size_t)e * DM * FFD;
  for (int k0 = 0; k0 < DM; k0 += 16) {
    float4 a = make_float4(0.f, 0.f, 0.f, 0.f);
    if (arp) a = *(const float4*)&arp[k0 + akf];
    As[akf + 0][arow] = a.x; As[akf + 1][arow] = a.y;
    As[akf + 2][arow] = a.z; As[akf + 3][arow] = a.w;
    *(float4*)&Bg[bk][bnf] = *(const float4*)&gwe[(size_t)(k0 + bk) * FFD + n0 + bnf];
    *(float4*)&Bu[bk][bnf] = *(const float4*)&uwe[(size_t)(k0 + bk) * FFD + n0 + bnf];
    __syncthreads();
#pragma unroll
    for (int k = 0; k < 16; ++k) {
      float4 av = *(const float4*)&As[k][ty * 4];
      float4 bg = *(const float4*)&Bg[k][tx * 4];
      float4 bu = *(const float4*)&Bu[k][tx * 4];
      float avv[4] = {av.x, av.y, av.z, av.w};
      float bgv[4] = {bg.x, bg.y, bg.z, bg.w};
      float buv[4] = {bu.x, bu.y, bu.z, bu.w};
#pragma unroll
      for (int i = 0; i < 4; ++i)
#pragma unroll
        for (int j = 0; j < 4; ++j) {
          aG[i][j] += avv[i] * bgv[j];
          aU[i][j] += avv[i] * buv[j];
        }
    }
    __syncthreads();
  }
  int off = offs[e];
#pragma unroll
  for (int i = 0; i < 4; ++i) {
    int r = m0 + ty * 4 + i;
    if (r < cnt) {
      float o[4];
#pragma unroll
      for (int j = 0; j < 4; ++j) {
        float g = aG[i][j];
        o[j] = (g / (1.f + expf(-g))) * aU[i][j];
      }
      *(float4*)&H[(size_t)(off + r) * FFD + n0 + tx * 4] = make_float4(o[0], o[1], o[2], o[3]);
    }
  }
}

__global__ __launch_bounds__(256) void k_moe_down(const float* __restrict__ H,
    const float* __restrict__ dw, const int* __restrict__ counts,
    const int* __restrict__ offs, float* __restrict__ eo) {
  int e = blockIdx.z;
  int cnt = counts[e];
  int m0 = blockIdx.y * 64;
  if (m0 >= cnt) return;
  int n0 = blockIdx.x * 64;
  __shared__ float As[16][64], Bs[16][64];
  int tid = threadIdx.x;
  int ty = tid >> 4, tx = tid & 15;
  int arow = tid >> 2, akf = (tid & 3) * 4;
  int bk = tid >> 4, bnf = (tid & 15) * 4;
  float acc[4][4] = {};
  int off = offs[e];
  int grow = m0 + arow;
  const float* arp = (grow < cnt) ? &H[(size_t)(off + grow) * FFD] : nullptr;
  const float* dwe = dw + (size_t)e * FFD * DM;
  for (int k0 = 0; k0 < FFD; k0 += 16) {
    float4 a = make_float4(0.f, 0.f, 0.f, 0.f);
    if (arp) a = *(const float4*)&arp[k0 + akf];
    As[akf + 0][arow] = a.x; As[akf + 1][arow] = a.y;
    As[akf + 2][arow] = a.z; As[akf + 3][arow] = a.w;
    *(float4*)&Bs[bk][bnf] = *(const float4*)&dwe[(size_t)(k0 + bk) * DM + n0 + bnf];
    __syncthreads();
#pragma unroll
    for (int k = 0; k < 16; ++k) {
      float4 av = *(const float4*)&As[k][ty * 4];
      float4 bv = *(const float4*)&Bs[k][tx * 4];
      float avv[4] = {av.x, av.y, av.z, av.w};
      float bvv[4] = {bv.x, bv.y, bv.z, bv.w};
#pragma unroll
      for (int i = 0; i < 4; ++i)
#pragma unroll
        for (int j = 0; j < 4; ++j) acc[i][j] += avv[i] * bvv[j];
    }
    __syncthreads();
  }
#pragma unroll
  for (int i = 0; i < 4; ++i) {
    int r = m0 + ty * 4 + i;
    if (r < cnt)
      *(float4*)&eo[(size_t)(off + r) * DM + n0 + tx * 4] =
          make_float4(acc[i][0], acc[i][1], acc[i][2], acc[i][3]);
  }
}

__global__ __launch_bounds__(256) void k_combine(const float* __restrict__ eo,
    const int* __restrict__ topi, const float* __restrict__ topw,
    const int* __restrict__ posb, const int* __restrict__ offs, float* __restrict__ x) {
  int t = blockIdx.x;
  int r0 = offs[topi[2 * t]] + posb[2 * t];
  int r1 = offs[topi[2 * t + 1]] + posb[2 * t + 1];
  float w0 = topw[2 * t], w1 = topw[2 * t + 1];
  for (int d = threadIdx.x; d < DM; d += 256)
    x[t * DM + d] += w0 * eo[(size_t)r0 * DM + d] + w1 * eo[(size_t)r1 * DM + d];
}

// ================= bf16 LM-head path (r4 verbatim, under test) =================
__global__ __launch_bounds__(256) void k_rmsnorm_b(const float* __restrict__ x,
    const float* __restrict__ w, ushort* __restrict__ y) {
  __shared__ float red[256];
  int t = blockIdx.x, tid = threadIdx.x;
  float ss = 0.f;
  for (int d = tid; d < DM; d += 256) { float v = x[t * DM + d]; ss += v * v; }
  red[tid] = ss; __syncthreads();
  for (int s = 128; s > 0; s >>= 1) { if (tid < s) red[tid] += red[tid + s]; __syncthreads(); }
  float inv = 1.0f / sqrtf(red[0] / (float)DM + REPS);
  for (int d = tid; d < DM; d += 256)
    y[t * DM + d] = f2b(w[d] * x[t * DM + d] * inv);
}

__global__ __launch_bounds__(256) void k_tconv(const float* __restrict__ in,
    ushort* __restrict__ out, int K, int ns, int mode) {
  __shared__ float tile[32][33];
  int n0 = blockIdx.x * 32, k0 = blockIdx.y * 32;
  int c = threadIdx.x & 31, rq = threadIdx.x >> 5;
#pragma unroll
  for (int rr = rq; rr < 32; rr += 8)
    tile[rr][c] = in[(size_t)(k0 + rr) * ns + n0 + c];
  __syncthreads();
#pragma unroll
  for (int rr = rq; rr < 32; rr += 8) {
    int n = n0 + rr;
    int orow = (mode == 0) ? n : (((n >> 4) << 5) + ((mode == 1) ? 0 : 16) + (n & 15));
    out[(size_t)orow * K + k0 + c] = f2b(tile[c][rr]);
  }
}

#define EPI_F32  2

template<int EPI, int RM>
__global__ __launch_bounds__(256) void k_gmm(
    const ushort* __restrict__ A, const ushort* __restrict__ Bt,
    ushort* __restrict__ Cb, float* __restrict__ Cf,
    int M, int K, int ldc, int e_arg,
    const int* __restrict__ slot, const int* __restrict__ counts,
    const int* __restrict__ offs) {
  int e = e_arg; (void)e; (void)slot; (void)counts; (void)offs; (void)Cb;
  int cnt = M;
  int m0 = blockIdx.y * 128;
  if (m0 >= cnt) return;
  int n0 = blockIdx.x * 128;

  __shared__ __align__(16) ushort As[128 * 40];
  __shared__ __align__(16) ushort Bs[128 * 40];

  int tid = threadIdx.x;
  int wave = tid >> 6, lane = tid & 63;
  int wr = wave >> 1, wc = wave & 1;
  (void)wave;

  int ar1 = tid >> 2, ar2 = ar1 + 64, kc = tid & 3;
  const ushort* Arow1 = A + (size_t)(m0 + ar1) * K;
  const ushort* Arow2 = A + (size_t)(m0 + ar2) * K;
  const ushort* Brow1 = Bt + (size_t)(n0 + ar1) * K;
  const ushort* Brow2 = Bt + (size_t)(n0 + ar2) * K;

  f32x4 zr = {0.f, 0.f, 0.f, 0.f};
  f32x4 acc[4][4];
#pragma unroll
  for (int i = 0; i < 4; ++i)
#pragma unroll
    for (int j = 0; j < 4; ++j) acc[i][j] = zr;

  int rl = lane & 15, g = lane >> 4;
  for (int k0 = 0; k0 < K; k0 += 32) {
    s16x8 va1 = *(const s16x8*)(Arow1 + k0 + kc * 8);
    s16x8 va2 = *(const s16x8*)(Arow2 + k0 + kc * 8);
    s16x8 vb1 = *(const s16x8*)(Brow1 + k0 + kc * 8);
    s16x8 vb2 = *(const s16x8*)(Brow2 + k0 + kc * 8);
    __syncthreads();
    *(s16x8*)&As[ar1 * 40 + kc * 8] = va1;
    *(s16x8*)&As[ar2 * 40 + kc * 8] = va2;
    *(s16x8*)&Bs[ar1 * 40 + kc * 8] = vb1;
    *(s16x8*)&Bs[ar2 * 40 + kc * 8] = vb2;
    __syncthreads();
    s16x8 av[4], bv[4];
#pragma unroll
    for (int mi = 0; mi < 4; ++mi)
      av[mi] = *(const s16x8*)&As[(wr * 64 + mi * 16 + rl) * 40 + g * 8];
#pragma unroll
    for (int ni = 0; ni < 4; ++ni)
      bv[ni] = *(const s16x8*)&Bs[(wc * 64 + ni * 16 + rl) * 40 + g * 8];
#pragma unroll
    for (int mi = 0; mi < 4; ++mi)
#pragma unroll
      for (int ni = 0; ni < 4; ++ni)
        acc[mi][ni] = __builtin_amdgcn_mfma_f32_16x16x32_bf16(av[mi], bv[ni], acc[mi][ni], 0, 0, 0);
  }

  int rg4 = (lane >> 4) * 4;
#pragma unroll
  for (int mi = 0; mi < 4; ++mi) {
#pragma unroll
    for (int rg = 0; rg < 4; ++rg) {
      int rloc = m0 + wr * 64 + mi * 16 + rg4 + rg;
#pragma unroll
      for (int ni = 0; ni < 4; ++ni)
        Cf[(size_t)rloc * ldc + n0 + wc * 64 + ni * 16 + rl] = acc[mi][ni][rg];
    }
  }
}

extern "C" void kernel_launch(void* const* d_in, const int* in_sizes, int n_in,
                              void* d_out, int out_size, void* d_ws, size_t ws_size,
                              hipStream_t stream) {
  (void)in_sizes; (void)n_in; (void)out_size; (void)ws_size;
  const int*   ids = (const int*)d_in[0];
  const float* tok = (const float*)d_in[1];
  const float* pos = (const float*)d_in[2];
  const float* wq  = (const float*)d_in[3];
  const float* wk  = (const float*)d_in[4];
  const float* wv  = (const float*)d_in[5];
  const float* wo  = (const float*)d_in[6];
  const float* n1w = (const float*)d_in[7];
  const float* n2w = (const float*)d_in[8];
  const float* rw  = (const float*)d_in[9];
  const float* gw  = (const float*)d_in[10];
  const float* uw  = (const float*)d_in[11];
  const float* dw  = (const float*)d_in[12];
  const float* fnw = (const float*)d_in[13];
  const float* lmw = (const float*)d_in[14];
  float* out = (float*)d_out;

  char* p = (char*)d_ws;
  auto alloc = [&](size_t bytes) { char* r = p; p += (bytes + 255) & ~(size_t)255; return r; };
  float* x    = (float*)alloc((size_t)TT * DM * 4);
  float* xn   = (float*)alloc((size_t)TT * DM * 4);
  float* q    = (float*)alloc((size_t)TT * DM * 4);
  float* kx   = (float*)alloc((size_t)TT * DM * 4);
  float* vx   = (float*)alloc((size_t)TT * DM * 4);
  float* ao   = (float*)alloc((size_t)TT * DM * 4);
  float* Hbuf = (float*)alloc((size_t)2 * TT * FFD * 4);
  float* eo   = (float*)alloc((size_t)2 * TT * DM * 4);
  float* topw = (float*)alloc((size_t)2 * TT * 4);
  int* topi   = (int*)alloc((size_t)2 * TT * 4);
  int* posb   = (int*)alloc((size_t)2 * TT * 4);
  int* slot   = (int*)alloc((size_t)NE * TT * 4);
  int* counts = (int*)alloc(256);
  int* offs   = (int*)alloc(256);
  ushort* xnb  = (ushort*)alloc((size_t)TT * DM * 2);
  ushort* wexp = (ushort*)alloc((size_t)2 * FFD * DM * 2);  // LM-head chunk Bt (3200x768 fits)

  k_embed<<<TT, 256, 0, stream>>>(ids, tok, pos, x);
  dim3 g12(DM / 64, TT / 64);
  for (int l = 0; l < NL; ++l) {
    k_rmsnorm<<<TT, 256, 0, stream>>>(x, n1w + l * DM, xn);
    k_gemm64<<<g12, 256, 0, stream>>>(xn, wq + (size_t)l * DM * DM, nullptr, q,  TT, DM, DM);
    k_gemm64<<<g12, 256, 0, stream>>>(xn, wk + (size_t)l * DM * DM, nullptr, kx, TT, DM, DM);
    k_gemm64<<<g12, 256, 0, stream>>>(xn, wv + (size_t)l * DM * DM, nullptr, vx, TT, DM, DM);
    k_attn<<<NB * NH * SQ, 256, 0, stream>>>(q, kx, vx, ao);
    k_gemm64<<<g12, 256, 0, stream>>>(ao, wo + (size_t)l * DM * DM, x, x, TT, DM, DM);
    k_rmsnorm<<<TT, 256, 0, stream>>>(x, n2w + l * DM, xn);
    k_zero8<<<1, 64, 0, stream>>>(counts);
    k_router<<<TT, 64, 0, stream>>>(xn, rw + (size_t)l * DM * NE, topi, topw, posb, slot, counts);
    k_offsets<<<1, 1, 0, stream>>>(counts, offs);
    k_moe_gu<<<dim3(FFD / 64, TT / 64, NE), 256, 0, stream>>>(
        xn, gw + (size_t)l * NE * DM * FFD, uw + (size_t)l * NE * DM * FFD,
        slot, counts, offs, Hbuf);
    k_moe_down<<<dim3(DM / 64, TT / 64, NE), 256, 0, stream>>>(
        Hbuf, dw + (size_t)l * NE * FFD * DM, counts, offs, eo);
    k_combine<<<TT, 256, 0, stream>>>(eo, topi, topw, posb, offs, x);
  }

  // LM head: bf16 MFMA path (the component under test)
  k_rmsnorm_b<<<TT, 256, 0, stream>>>(x, fnw, xnb);
  for (int c = 0; c < NV / LMC; ++c) {
    k_tconv<<<dim3(LMC / 32, 24), 256, 0, stream>>>(lmw + c * LMC, wexp, DM, NV, 0);
    k_gmm<EPI_F32, 0><<<dim3(LMC / 128, 8), 256, 0, stream>>>(
        xnb, wexp, nullptr, out + c * LMC, TT, DM, NV, 0, nullptr, nullptr, nullptr);
  }
}